// Round 3
// baseline (340.793 us; speedup 1.0000x reference)
//
#include <hip/hip_runtime.h>

#define Hh 64
#define Ww 64
#define Cc 512
#define Bb 16
#define NTOK (1 + Hh * Ww)   // 4097
#define TW 8                 // outputs per thread along w
#define TH 8                 // outputs per thread along h

// ---------------------------------------------------------------------------
// Prep kernel (unchanged): combine w7 + padded w5 + padded w3 + identity into
// one effective 7x7 kernel per channel, stored TRANSPOSED [tap][channel] so
// conv-side tap reads are coalesced (lane = channel). Combine biases, copy
// cls tokens through.
// ---------------------------------------------------------------------------
__global__ void ppeg_prep(const float* __restrict__ w7, const float* __restrict__ b7,
                          const float* __restrict__ w5, const float* __restrict__ b5,
                          const float* __restrict__ w3, const float* __restrict__ b3,
                          const float* __restrict__ x, float* __restrict__ wt,
                          float* __restrict__ beff, float* __restrict__ out) {
    int idx = blockIdx.x * blockDim.x + threadIdx.x;
    if (idx < Cc * 49) {
        int c = idx / 49, t = idx % 49;
        int r = t / 7, s = t % 7;
        float v = w7[idx];
        if (r >= 1 && r <= 5 && s >= 1 && s <= 5) v += w5[c * 25 + (r - 1) * 5 + (s - 1)];
        if (r >= 2 && r <= 4 && s >= 2 && s <= 4) v += w3[c * 9 + (r - 2) * 3 + (s - 2)];
        if (t == 24) v += 1.0f;               // identity (center tap)
        wt[t * Cc + c] = v;                   // transposed store
    }
    if (idx < Cc) beff[idx] = b7[idx] + b5[idx] + b3[idx];
    if (idx < Bb * Cc) {
        int b = idx / Cc, c = idx % Cc;
        size_t o = (size_t)b * NTOK * Cc + c;
        out[o] = x[o];                        // cls token pass-through
    }
}

// ---------------------------------------------------------------------------
// Conv kernel v4: row streaming + explicit 1-row prefetch, occupancy PINNED.
//
// History of compiler register-heuristic sabotage on this kernel:
//   R0: default heuristics -> 32 VGPR, burst-and-drain, latency-bound.
//   R2: __launch_bounds__(64,4) set budget 128 but no MAX occupancy ->
//       allocator squeezed to 64 VGPR chasing 8 waves/SIMD -> spills
//       (WRITE_SIZE 131->226 MB of scratch traffic), 170 us.
// Fix: amdgpu_waves_per_eu(4,4) pins BOTH min and max -> 128-VGPR budget
// and no incentive to shrink below it. Live set ~110 regs: acc[64] +
// vbuf[28] + addressing. 4 waves/SIMD = 50% occupancy BY DESIGN.
//
// Explicit double-buffered row prefetch (vbuf[2][14], static k&1 index after
// full unroll): row k+1's 14 loads issue before row k's ~448 FMA cycles, so
// a wave self-hides ~half the ~900-cy HBM latency; 4 resident waves hide the
// rest. Taps re-read from the transposed slab (12.5 KB/64ch, L1-hot) as the
// v2 measurement showed the allocator prefers.
// 1-wave blocks, 8192-block grid: w-fast layout -> each XCD gets a column
// strip per (cblk,b), vertical halo re-reads hit that XCD's L2; nontemporal
// output stores keep the L3 input-resident for horizontal halo.
// ---------------------------------------------------------------------------
__global__ __launch_bounds__(64)
__attribute__((amdgpu_waves_per_eu(4, 4)))
void ppeg_conv(const float* __restrict__ x, const float* __restrict__ wt,
               const float* __restrict__ beff, float* __restrict__ out) {
    const int tx = threadIdx.x;        // channel lane 0..63
    const int c  = blockIdx.y * 64 + tx;
    const int b  = blockIdx.z;
    const int sp = blockIdx.x;         // 0..63 : 8 h-blocks x 8 w-tiles
    const int wblk = sp & 7;           // fast dim
    const int hblk = sp >> 3;
    const int oh0   = hblk * TH;       // first of TH output rows
    const int wbase = wblk * TW;

    const float* xb = x + ((size_t)b * NTOK + 1) * Cc + c;   // pixel (0,0), ch c

    const float bias = beff[c];
    float acc[TH][TW];
#pragma unroll
    for (int o = 0; o < TH; ++o)
#pragma unroll
        for (int j = 0; j < TW; ++j) acc[o][j] = bias;

    const bool interior = (wblk != 0) && (wblk != 7);

    float vbuf[2][TW + 6];             // double-buffered input row window

    auto loadrow = [&](float* __restrict__ v, int k) {
        const int ir = oh0 + k - 3;
        if (ir < 0 || ir >= Hh) return;            // wave-uniform
        const float* xrow = xb + (size_t)ir * (Ww * Cc);
        if (interior) {
#pragma unroll
            for (int j = 0; j < TW + 6; ++j)
                v[j] = xrow[(size_t)(wbase - 3 + j) * Cc];
        } else {
#pragma unroll
            for (int j = 0; j < TW + 6; ++j) {
                const int wc = wbase + j - 3;
                v[j] = (wc >= 0 && wc < Ww) ? xrow[(size_t)wc * Cc] : 0.0f;
            }
        }
    };

    loadrow(vbuf[0], 0);               // prologue: first row in flight

    // Row k feeds output rows o in [k-6, k] (tap row r = k-o).
    // Full unroll -> all vbuf indices (k&1) are compile-time constants.
#pragma unroll
    for (int k = 0; k < TH + 6; ++k) {
        if (k + 1 < TH + 6) loadrow(vbuf[(k + 1) & 1], k + 1);   // prefetch
        const int ir = oh0 + k - 3;
        if (ir >= 0 && ir < Hh) {                   // wave-uniform
            const float* v = vbuf[k & 1];
#pragma unroll
            for (int o = 0; o < TH; ++o) {
                if (o > k || o < k - 6) continue;   // static after unroll
                const int r = k - o;
#pragma unroll
                for (int s = 0; s < 7; ++s) {
                    const float tp = wt[(r * 7 + s) * Cc + c];
#pragma unroll
                    for (int j = 0; j < TW; ++j)
                        acc[o][j] = fmaf(tp, v[j + s], acc[o][j]);
                }
            }
        }
    }

#pragma unroll
    for (int o = 0; o < TH; ++o) {
        float* orow = out + ((size_t)b * NTOK + 1 + (size_t)(oh0 + o) * Ww + wbase) * Cc + c;
#pragma unroll
        for (int j = 0; j < TW; ++j)
            __builtin_nontemporal_store(acc[o][j], &orow[(size_t)j * Cc]);
    }
}

extern "C" void kernel_launch(void* const* d_in, const int* in_sizes, int n_in,
                              void* d_out, int out_size, void* d_ws, size_t ws_size,
                              hipStream_t stream) {
    const float* x  = (const float*)d_in[0];
    const float* w7 = (const float*)d_in[1];
    const float* b7 = (const float*)d_in[2];
    const float* w5 = (const float*)d_in[3];
    const float* b5 = (const float*)d_in[4];
    const float* w3 = (const float*)d_in[5];
    const float* b3 = (const float*)d_in[6];
    float* out = (float*)d_out;

    float* wt   = (float*)d_ws;          // 49*Cc floats, transposed [tap][channel]
    float* beff = wt + 49 * Cc;          // Cc floats

    ppeg_prep<<<(Cc * 49 + 255) / 256, 256, 0, stream>>>(w7, b7, w5, b5, w3, b3,
                                                         x, wt, beff, out);

    // 1-wave blocks: (8 hblk x 8 wblk) x 8 cblk x 16 b = 8192 blocks.
    dim3 grid(64, Cc / 64, Bb);
    dim3 block(64, 1);
    ppeg_conv<<<grid, block, 0, stream>>>(x, wt, beff, out);
}

// Round 4
// 279.571 us; speedup vs baseline: 1.2190x; 1.2190x over previous
//
#include <hip/hip_runtime.h>

#define Hh 64
#define Ww 64
#define Cc 512
#define Bb 16
#define NTOK (1 + Hh * Ww)   // 4097
#define TW 8                 // output pixels per thread along w
#define TH 4                 // output pixels per thread along h

typedef float v2f __attribute__((ext_vector_type(2)));

// ---------------------------------------------------------------------------
// Prep kernel (unchanged): combine w7 + padded w5 + padded w3 + identity into
// one effective 7x7 kernel per channel, stored TRANSPOSED [tap][channel] so
// conv-side tap reads are coalesced (lane = channel pair). Combine biases,
// copy cls tokens through.
// ---------------------------------------------------------------------------
__global__ void ppeg_prep(const float* __restrict__ w7, const float* __restrict__ b7,
                          const float* __restrict__ w5, const float* __restrict__ b5,
                          const float* __restrict__ w3, const float* __restrict__ b3,
                          const float* __restrict__ x, float* __restrict__ wt,
                          float* __restrict__ beff, float* __restrict__ out) {
    int idx = blockIdx.x * blockDim.x + threadIdx.x;
    if (idx < Cc * 49) {
        int c = idx / 49, t = idx % 49;
        int r = t / 7, s = t % 7;
        float v = w7[idx];
        if (r >= 1 && r <= 5 && s >= 1 && s <= 5) v += w5[c * 25 + (r - 1) * 5 + (s - 1)];
        if (r >= 2 && r <= 4 && s >= 2 && s <= 4) v += w3[c * 9 + (r - 2) * 3 + (s - 2)];
        if (t == 24) v += 1.0f;               // identity (center tap)
        wt[t * Cc + c] = v;                   // transposed store
    }
    if (idx < Cc) beff[idx] = b7[idx] + b5[idx] + b3[idx];
    if (idx < Bb * Cc) {
        int b = idx / Cc, c = idx % Cc;
        size_t o = (size_t)b * NTOK * Cc + c;
        out[o] = x[o];                        // cls token pass-through
    }
}

// ---------------------------------------------------------------------------
// Conv kernel v5: R1 shell (256-thread blocks — the ONLY workgroup shape the
// allocator treats sanely: wgsize=64 triggered a 64-reg squeeze + spills in
// R2/R3 even with waves_per_eu(4,4); wgsize=256 gave 96 regs, zero spill)
// + float2-per-lane channel vectorization + LDS tap cache.
//
//  - Each lane owns TWO adjacent channels: global loads are dwordx2
//    (512 B per wave-instruction vs 256 B before) -> 2x bytes in flight at
//    the same wave residency; load-instruction count halves. This attacks
//    R1's measured limiter: ~6 KB in flight per CU vs the ~12.3 KB needed
//    to reach the ~6.3 TB/s achievable BW (R1: 2.7 TB/s, 33%).
//  - Block covers 128 channels -> tap slab is 25 KB, too big to stay in L1
//    against the streaming input (L2 fallback would add ~2 GB aggregate tap
//    traffic ~= 58 us of L2 time). Stage it in LDS once per block; per-use
//    ds_read_b64 (4-way bank alias = 1.58x on the far-from-critical LDS
//    pipe, ~14 us aggregate, fully overlapped).
//  - Row-streaming 4x8 tile: each of the 10 input rows loaded once (14
//    dwordx2), feeds up to 7 output rows (~628 FMA-cycles per burst) ->
//    bursts from 4 co-resident waves cover the ~500 cy HBM latency.
//  - Nontemporal output stores keep the input L3-resident for halo re-reads.
// ---------------------------------------------------------------------------
__global__ __launch_bounds__(256, 2)
void ppeg_conv(const float* __restrict__ x, const float* __restrict__ wt,
               const float* __restrict__ beff, float* __restrict__ out) {
    const int tx = threadIdx.x;        // channel-pair lane 0..63
    const int ty = threadIdx.y;        // h-strip 0..3 (wave-uniform)
    const int cb = blockIdx.y * 128;
    const int c0 = cb + 2 * tx;        // first of this lane's two channels
    const int b  = blockIdx.z;
    const int sp = blockIdx.x;         // 0..31 : 4 h-blocks x 8 w-tiles
    const int wblk = sp & 7;
    const int hblk = sp >> 3;
    const int oh0   = hblk * (TH * 4) + ty * TH;   // first of TH output rows
    const int wbase = wblk * TW;

    // Stage the block's 49x128 tap slab into LDS (once), coalesced.
    __shared__ float taps[49][128];
    const int tid = ty * 64 + tx;
    for (int idx = tid; idx < 49 * 128; idx += 256) {
        const int t = idx >> 7, ch = idx & 127;
        taps[t][ch] = wt[t * Cc + cb + ch];
    }
    __syncthreads();

    const float* xb = x + ((size_t)b * NTOK + 1) * Cc + c0;  // pixel (0,0)

    const v2f bias = *(const v2f*)&beff[c0];
    v2f acc[TH][TW];
#pragma unroll
    for (int o = 0; o < TH; ++o)
#pragma unroll
        for (int j = 0; j < TW; ++j) acc[o][j] = bias;

    const bool interior = (wblk != 0) && (wblk != 7);

    // Stream input rows ir = oh0-3 .. oh0+TH+2. Row k feeds output rows
    // o in [k-6, k] (tap row r = k-o). All indices static after unroll.
#pragma unroll
    for (int k = 0; k < TH + 6; ++k) {
        const int ir = oh0 + k - 3;
        if (ir >= 0 && ir < Hh) {              // wave-uniform (oh0 fixed/wave)
            const float* xrow = xb + (size_t)ir * (Ww * Cc);
            v2f v[TW + 6];
            if (interior) {
#pragma unroll
                for (int j = 0; j < TW + 6; ++j)
                    v[j] = *(const v2f*)(xrow + (size_t)(wbase - 3 + j) * Cc);
            } else {
#pragma unroll
                for (int j = 0; j < TW + 6; ++j) {
                    const int wc = wbase + j - 3;
                    if (wc >= 0 && wc < Ww)
                        v[j] = *(const v2f*)(xrow + (size_t)wc * Cc);
                    else {
                        v[j].x = 0.0f; v[j].y = 0.0f;
                    }
                }
            }
#pragma unroll
            for (int o = 0; o < TH; ++o) {
                if (o > k || o < k - 6) continue;   // static after unroll
                const int r = k - o;
#pragma unroll
                for (int s = 0; s < 7; ++s) {
                    const v2f tp = *(const v2f*)&taps[r * 7 + s][2 * tx];
#pragma unroll
                    for (int j = 0; j < TW; ++j) {
                        acc[o][j].x = fmaf(tp.x, v[j + s].x, acc[o][j].x);
                        acc[o][j].y = fmaf(tp.y, v[j + s].y, acc[o][j].y);
                    }
                }
            }
        }
    }

#pragma unroll
    for (int o = 0; o < TH; ++o) {
        float* orow = out + ((size_t)b * NTOK + 1 + (size_t)(oh0 + o) * Ww + wbase) * Cc + c0;
#pragma unroll
        for (int j = 0; j < TW; ++j)
            __builtin_nontemporal_store(acc[o][j], (v2f*)(orow + (size_t)j * Cc));
    }
}

extern "C" void kernel_launch(void* const* d_in, const int* in_sizes, int n_in,
                              void* d_out, int out_size, void* d_ws, size_t ws_size,
                              hipStream_t stream) {
    const float* x  = (const float*)d_in[0];
    const float* w7 = (const float*)d_in[1];
    const float* b7 = (const float*)d_in[2];
    const float* w5 = (const float*)d_in[3];
    const float* b5 = (const float*)d_in[4];
    const float* w3 = (const float*)d_in[5];
    const float* b3 = (const float*)d_in[6];
    float* out = (float*)d_out;

    float* wt   = (float*)d_ws;          // 49*Cc floats, transposed [tap][channel]
    float* beff = wt + 49 * Cc;          // Cc floats

    ppeg_prep<<<(Cc * 49 + 255) / 256, 256, 0, stream>>>(w7, b7, w5, b5, w3, b3,
                                                         x, wt, beff, out);

    // (4 hblk x 8 wblk) x 4 cblk x 16 b = 2048 blocks of 256 threads.
    dim3 grid(32, Cc / 128, Bb);
    dim3 block(64, 4);
    ppeg_conv<<<grid, block, 0, stream>>>(x, wt, beff, out);
}

// Round 5
// 271.096 us; speedup vs baseline: 1.2571x; 1.0313x over previous
//
#include <hip/hip_runtime.h>

#define Hh 64
#define Ww 64
#define Cc 512
#define Bb 16
#define NTOK (1 + Hh * Ww)   // 4097
#define TW 8                 // output pixels per thread along w
#define TH 4                 // output pixels per thread along h

typedef float v2f __attribute__((ext_vector_type(2)));

// ---------------------------------------------------------------------------
// Prep kernel (unchanged): combine w7 + padded w5 + padded w3 + identity into
// one effective 7x7 kernel per channel, stored TRANSPOSED [tap][channel] so
// conv-side tap reads are coalesced (lane = channel pair). Combine biases,
// copy cls tokens through.
// ---------------------------------------------------------------------------
__global__ void ppeg_prep(const float* __restrict__ w7, const float* __restrict__ b7,
                          const float* __restrict__ w5, const float* __restrict__ b5,
                          const float* __restrict__ w3, const float* __restrict__ b3,
                          const float* __restrict__ x, float* __restrict__ wt,
                          float* __restrict__ beff, float* __restrict__ out) {
    int idx = blockIdx.x * blockDim.x + threadIdx.x;
    if (idx < Cc * 49) {
        int c = idx / 49, t = idx % 49;
        int r = t / 7, s = t % 7;
        float v = w7[idx];
        if (r >= 1 && r <= 5 && s >= 1 && s <= 5) v += w5[c * 25 + (r - 1) * 5 + (s - 1)];
        if (r >= 2 && r <= 4 && s >= 2 && s <= 4) v += w3[c * 9 + (r - 2) * 3 + (s - 2)];
        if (t == 24) v += 1.0f;               // identity (center tap)
        wt[t * Cc + c] = v;                   // transposed store
    }
    if (idx < Cc) beff[idx] = b7[idx] + b5[idx] + b3[idx];
    if (idx < Bb * Cc) {
        int b = idx / Cc, c = idx % Cc;
        size_t o = (size_t)b * NTOK * Cc + c;
        out[o] = x[o];                        // cls token pass-through
    }
}

// ---------------------------------------------------------------------------
// Conv kernel v6 = v5 body + chunked XCD swizzle.
//
// v5 post-mortem: float2 lanes + LDS taps got 3.5 TB/s / 108 us, no spills
// (overflow live set parks in AGPRs -> arch-VGPR reads 64, ~16 waves/CU).
// Still latency-bound (VALU 25%, HBM 44%), and FETCH rose to 243 MB: 58% of
// raw input reads are HALO DUPLICATES, and with grid.x fastest + round-robin
// XCD dispatch, spatially adjacent blocks land on DIFFERENT XCDs -> halo
// re-reads miss the private L2 and pay ~600 cy L3/HBM latency.
//
// Fix (this round's single change): chunked XCD swizzle. One (cblk,b)
// group's whole input slab is 64x64x128ch x4B = 2 MB -- fits the 4 MB
// per-XCD L2. Remap so all 32 spatial blocks of a group run on ONE XCD,
// co-resident: h- and w-halo re-reads become L2 hits. Expect FETCH -> ~150
// MB (compulsory 134) and avg read latency ~600 -> ~350 cy, which directly
// scales a latency-bound kernel (rate = bytes-in-flight / latency).
// Mapping assumption: XCD = linear_workgroup_id % 8 (x fastest). Bijective
// since 2048 % 8 == 0. If FETCH doesn't move, the assumption is falsified.
// ---------------------------------------------------------------------------
__global__ __launch_bounds__(256, 2)
void ppeg_conv(const float* __restrict__ x, const float* __restrict__ wt,
               const float* __restrict__ beff, float* __restrict__ out) {
    const int tx = threadIdx.x;        // channel-pair lane 0..63
    const int ty = threadIdx.y;        // h-strip 0..3 (wave-uniform)

    // --- chunked XCD swizzle -------------------------------------------------
    // L: hardware linear workgroup id (x fastest) -> XCD = L % 8.
    // g_lin groups 32 consecutive same-XCD slots into one (cblk,b) group.
    const int L     = blockIdx.x + 32 * (blockIdx.y + 4 * blockIdx.z); // 0..2047
    const int g_lin = (L & 7) * 256 + (L >> 3);
    const int sp    = g_lin & 31;      // spatial block 0..31 within group
    const int g     = g_lin >> 5;      // 0..63 : (cblk, b) group
    const int cb    = (g & 3) * 128;
    const int b     = g >> 2;
    // ------------------------------------------------------------------------

    const int c0 = cb + 2 * tx;        // first of this lane's two channels
    const int wblk = sp & 7;
    const int hblk = sp >> 3;
    const int oh0   = hblk * (TH * 4) + ty * TH;   // first of TH output rows
    const int wbase = wblk * TW;

    // Stage the block's 49x128 tap slab into LDS (once), coalesced.
    __shared__ float taps[49][128];
    const int tid = ty * 64 + tx;
    for (int idx = tid; idx < 49 * 128; idx += 256) {
        const int t = idx >> 7, ch = idx & 127;
        taps[t][ch] = wt[t * Cc + cb + ch];
    }
    __syncthreads();

    const float* xb = x + ((size_t)b * NTOK + 1) * Cc + c0;  // pixel (0,0)

    const v2f bias = *(const v2f*)&beff[c0];
    v2f acc[TH][TW];
#pragma unroll
    for (int o = 0; o < TH; ++o)
#pragma unroll
        for (int j = 0; j < TW; ++j) acc[o][j] = bias;

    const bool interior = (wblk != 0) && (wblk != 7);

    // Stream input rows ir = oh0-3 .. oh0+TH+2. Row k feeds output rows
    // o in [k-6, k] (tap row r = k-o). All indices static after unroll.
#pragma unroll
    for (int k = 0; k < TH + 6; ++k) {
        const int ir = oh0 + k - 3;
        if (ir >= 0 && ir < Hh) {              // wave-uniform (oh0 fixed/wave)
            const float* xrow = xb + (size_t)ir * (Ww * Cc);
            v2f v[TW + 6];
            if (interior) {
#pragma unroll
                for (int j = 0; j < TW + 6; ++j)
                    v[j] = *(const v2f*)(xrow + (size_t)(wbase - 3 + j) * Cc);
            } else {
#pragma unroll
                for (int j = 0; j < TW + 6; ++j) {
                    const int wc = wbase + j - 3;
                    if (wc >= 0 && wc < Ww)
                        v[j] = *(const v2f*)(xrow + (size_t)wc * Cc);
                    else {
                        v[j].x = 0.0f; v[j].y = 0.0f;
                    }
                }
            }
#pragma unroll
            for (int o = 0; o < TH; ++o) {
                if (o > k || o < k - 6) continue;   // static after unroll
                const int r = k - o;
#pragma unroll
                for (int s = 0; s < 7; ++s) {
                    const v2f tp = *(const v2f*)&taps[r * 7 + s][2 * tx];
#pragma unroll
                    for (int j = 0; j < TW; ++j) {
                        acc[o][j].x = fmaf(tp.x, v[j + s].x, acc[o][j].x);
                        acc[o][j].y = fmaf(tp.y, v[j + s].y, acc[o][j].y);
                    }
                }
            }
        }
    }

#pragma unroll
    for (int o = 0; o < TH; ++o) {
        float* orow = out + ((size_t)b * NTOK + 1 + (size_t)(oh0 + o) * Ww + wbase) * Cc + c0;
#pragma unroll
        for (int j = 0; j < TW; ++j)
            __builtin_nontemporal_store(acc[o][j], (v2f*)(orow + (size_t)j * Cc));
    }
}

extern "C" void kernel_launch(void* const* d_in, const int* in_sizes, int n_in,
                              void* d_out, int out_size, void* d_ws, size_t ws_size,
                              hipStream_t stream) {
    const float* x  = (const float*)d_in[0];
    const float* w7 = (const float*)d_in[1];
    const float* b7 = (const float*)d_in[2];
    const float* w5 = (const float*)d_in[3];
    const float* b5 = (const float*)d_in[4];
    const float* w3 = (const float*)d_in[5];
    const float* b3 = (const float*)d_in[6];
    float* out = (float*)d_out;

    float* wt   = (float*)d_ws;          // 49*Cc floats, transposed [tap][channel]
    float* beff = wt + 49 * Cc;          // Cc floats

    ppeg_prep<<<(Cc * 49 + 255) / 256, 256, 0, stream>>>(w7, b7, w5, b5, w3, b3,
                                                         x, wt, beff, out);

    // (4 hblk x 8 wblk) x 4 cblk x 16 b = 2048 blocks of 256 threads.
    dim3 grid(32, Cc / 128, Bb);
    dim3 block(64, 4);
    ppeg_conv<<<grid, block, 0, stream>>>(x, wt, beff, out);
}